// Round 11
// baseline (496.560 us; speedup 1.0000x reference)
//
#include <hip/hip_runtime.h>
#include <hip/hip_bf16.h>

#define NTH     256
#define ROWS    32
#define NSTEPS  100
#define PITERS  50
#define LAMBDAV 0.1f

typedef __bf16 bf16x8 __attribute__((ext_vector_type(8)));
typedef float  f32x4  __attribute__((ext_vector_type(4)));

// R11: 32-row blocks x 256 threads (4 waves), grid 512 -> 2 INDEPENDENT
// blocks/CU (same 8 waves/CU as R10, but barrier drains + dependency stalls
// overlap across blocks). VGPR cap scales ~65536/NTH -> 256 at NTH=256, so
// the ~210-reg peak fits without spill (R4 spilled at cap 128).
// LDS map — audited, non-overlapping, 73728 B + ~2.3K arrays (< 80K -> 2/CU):
//   yh  bf16 [32][256] @0      (16384) stride 512
//   yl  bf16 [32][256] @16384  (16384) stride 512
//   whb bf16 [256][64] @32768  (32768) stride 128   (p2 A-hi)
//   rhb bf16 [32][64]  @65536  (4096)  stride 128
//   rlb bf16 [32][64]  @69632  (4096)  stride 128
//   wst fp32 [256][64] @0 (65536) overlays yh+yl+whb during init only.
// p1 W-frags (hi+lo) and p2 W-lo in registers; whb rebuilt from global after
// the wst overlay is consumed. All hot accesses XOR-swizzled by ((row&7)<<4).
// Persistent regs = 168 (wbh 32 + wbl 32 + w2lo 32 + xm 32 + ym 32 + nin 8).

__global__ __launch_bounds__(NTH, 2)
void fista11(const float* __restrict__ inp, const float* __restrict__ Wg,
             const float* __restrict__ X0, float* __restrict__ out)
{
    __shared__ __align__(16) char lds[73728];
    __shared__ __align__(16) float vf[256];
    __shared__ __align__(16) float up[256];
    __shared__ __align__(16) float uf[64];
    __shared__ float red[16];
    __shared__ float scal[2];

    char* const yhb = lds;
    char* const ylb = lds + 16384;
    char* const whb = lds + 32768;
    char* const rhb = lds + 65536;
    char* const rlb = lds + 69632;
    char* const wst = lds;            // fp32 W staging overlay (yh+yl+whb)

    const int tid  = threadIdx.x;
    const int w    = tid >> 6;        // 0..3
    const int lane = tid & 63;
    const int l4   = lane >> 4;       // 0..3
    const int ln   = lane & 15;       // 0..15
    const int rb   = blockIdx.x * ROWS;

    // phase-1: wave w -> n-tile w, m-tiles {0,1} (rows 0-15, 16-31)
    // phase-2': wave w -> dout-tiles {4w..4w+3}, row-tiles {0,1}

    // ---- stage W fp32 into LDS (swizzled) ----
    #pragma unroll
    for (int i = 0; i < 16; ++i) {
        int wi = (tid + i * NTH) * 4;
        int j = wi >> 6, k = wi & 63;
        f32x4 v = *(const f32x4*)&Wg[wi];
        *(f32x4*)(wst + j * 256 + ((k * 4) ^ ((j & 7) << 4))) = v;
    }

    // ---- per-thread constants (global reads before any LDS dependency) ----
    float nin[2][4];                           // -in, phase-1 D layout
    #pragma unroll
    for (int s = 0; s < 2; ++s)
        #pragma unroll
        for (int r = 0; r < 4; ++r)
            nin[s][r] = -inp[(size_t)(rb + s * 16 + 4 * l4 + r) * 64 + w * 16 + ln];

    float xm[4][2][4], ym[4][2][4];            // phase-2' D layout: [dt][rt][r]
    #pragma unroll
    for (int dt = 0; dt < 4; ++dt)
      #pragma unroll
      for (int rt = 0; rt < 2; ++rt) {
          f32x4 x = *(const f32x4*)&X0[(size_t)(rb + 16 * rt + ln) * 256 + (4 * w + dt) * 16 + 4 * l4];
          #pragma unroll
          for (int r = 0; r < 4; ++r) { xm[dt][rt][r] = x[r]; ym[dt][rt][r] = x[r]; }
      }

    if (tid < 256) vf[tid] = 0.0625f;          // ones/sqrt(256)
    __syncthreads();

    // ---- Lipschitz: 50 power iterations of Q = 2 W W^T (R2-verified) ----
    for (int it = 0; it <= PITERS; ++it) {
        {                                      // partial u = W^T v (4-way j split)
            int col = tid & 63, jq = tid >> 6;
            float s = 0.f;
            #pragma unroll 4
            for (int j = jq * 64; j < jq * 64 + 64; ++j)
                s += vf[j] * *(const float*)(wst + j * 256 + ((col * 4) ^ ((j & 7) << 4)));
            up[tid] = s;
        }
        __syncthreads();
        if (tid < 64) uf[tid] = up[tid] + up[tid + 64] + up[tid + 128] + up[tid + 192];
        __syncthreads();
        float w2;
        {                                      // w2 = 2 * W[tid,:] . u
            float s = 0.f;
            #pragma unroll
            for (int kc = 0; kc < 64; kc += 4) {
                f32x4 wv = *(const f32x4*)(wst + tid * 256 + ((kc * 4) ^ ((tid & 7) << 4)));
                f32x4 u4 = *(const f32x4*)&uf[kc];
                s += wv.x * u4.x + wv.y * u4.y + wv.z * u4.z + wv.w * u4.w;
            }
            w2 = 2.f * s;
        }
        float sq = (it == PITERS) ? vf[tid] * w2 : w2 * w2;
        #pragma unroll
        for (int off = 32; off >= 1; off >>= 1) sq += __shfl_down(sq, off);
        if (lane == 0) red[w] = sq;
        __syncthreads();
        float tot = red[0] + red[1] + red[2] + red[3];
        if (it < PITERS) {
            vf[tid] = w2 * (1.f / sqrtf(tot));
        } else if (tid == 0) {
            scal[0] = 1.f / tot;               // invL (Rayleigh quotient)
            scal[1] = LAMBDAV / tot;           // thr
        }
        __syncthreads();
    }

    // ---- phase-1 W frags (col n-tile w, K=256) -> regs (hi+lo, 64 VGPR) ----
    bf16x8 wbh[8], wbl[8];
    #pragma unroll
    for (int c = 0; c < 8; ++c) {
        bf16x8 ph{}, pl{};
        #pragma unroll
        for (int t = 0; t < 8; ++t) {
            int j = 32 * c + 8 * l4 + t;
            float wv = *(const float*)(wst + j * 256 + (((w * 16 + ln) * 4) ^ ((j & 7) << 4)));
            __bf16 h = (__bf16)wv;
            ph[t] = h; pl[t] = (__bf16)(wv - (float)h);
        }
        wbh[c] = ph; wbl[c] = pl;
    }
    // ---- phase-2 W-lo frags (dout-tiles 4w..4w+3) -> regs (32 VGPR) ----
    bf16x8 w2lo[4][2];
    #pragma unroll
    for (int dt = 0; dt < 4; ++dt) {
        const int brow = (4 * w + dt) * 16 + ln;
        #pragma unroll
        for (int kc = 0; kc < 2; ++kc) {
            bf16x8 p{};
            #pragma unroll
            for (int t = 0; t < 8; ++t) {
                int k = kc * 32 + 8 * l4 + t;
                float wv = *(const float*)(wst + brow * 256 + ((k * 4) ^ ((brow & 7) << 4)));
                __bf16 h = (__bf16)wv;
                p[t] = (__bf16)(wv - (float)h);
            }
            w2lo[dt][kc] = p;
        }
    }
    __syncthreads();   // ALL wst consumers done; overlay region free

    // ---- build whb (W-hi plane) from global (L2-hot) + y0 into yh/yl ----
    #pragma unroll
    for (int i = 0; i < 16; ++i) {
        int wi = (tid + i * NTH) * 4;
        int j = wi >> 6, k0 = wi & 63;
        f32x4 v = *(const f32x4*)&Wg[wi];
        unsigned short h0 = __builtin_bit_cast(unsigned short, (__bf16)v.x);
        unsigned short h1 = __builtin_bit_cast(unsigned short, (__bf16)v.y);
        unsigned short h2 = __builtin_bit_cast(unsigned short, (__bf16)v.z);
        unsigned short h3 = __builtin_bit_cast(unsigned short, (__bf16)v.w);
        uint2 H; H.x = h0 | ((unsigned)h1 << 16); H.y = h2 | ((unsigned)h3 << 16);
        *(uint2*)(whb + j * 128 + ((k0 * 2) ^ ((j & 7) << 4))) = H;
    }
    #pragma unroll
    for (int dt = 0; dt < 4; ++dt)
      #pragma unroll
      for (int rt = 0; rt < 2; ++rt) {
          const int row  = 16 * rt + ln;
          const int colb = ((4 * w + dt) * 16 + 4 * l4) * 2;
          unsigned short hb[4], lb[4];
          #pragma unroll
          for (int r = 0; r < 4; ++r) {
              float v = ym[dt][rt][r];
              __bf16 h = (__bf16)v;
              hb[r] = __builtin_bit_cast(unsigned short, h);
              lb[r] = __builtin_bit_cast(unsigned short, (__bf16)(v - (float)h));
          }
          const int off = row * 512 + (colb ^ ((row & 7) << 4));
          uint2 H, L;
          H.x = hb[0] | ((unsigned)hb[1] << 16); H.y = hb[2] | ((unsigned)hb[3] << 16);
          L.x = lb[0] | ((unsigned)lb[1] << 16); L.y = lb[2] | ((unsigned)lb[3] << 16);
          *(uint2*)(yhb + off) = H;
          *(uint2*)(ylb + off) = L;
      }
    __syncthreads();

    const float c2  = 2.f * scal[0];
    const float thr = scal[1];
    const int r0row = ln;                      // phase-1 A rows (m-tile 0)
    const int r1row = 16 + ln;                 // m-tile 1
    const int x0 = (r0row & 7) << 4, x1 = (r1row & 7) << 4;
    const int rx = (ln & 7) << 4;              // swizzle for 128B-stride planes

    float tt_ = 1.f;
    for (int step = 0; step < NSTEPS; ++step) {
        // ======== phase 1: R = y W - in  (two 16x16 tiles per wave) ========
        f32x4 acc0 = { nin[0][0], nin[0][1], nin[0][2], nin[0][3] };
        f32x4 acc1 = { nin[1][0], nin[1][1], nin[1][2], nin[1][3] };
        #pragma unroll
        for (int c = 0; c < 8; ++c) {
            const int kb = c * 64 + l4 * 16;
            bf16x8 a0h = *(const bf16x8*)(yhb + r0row * 512 + (kb ^ x0));
            bf16x8 a0l = *(const bf16x8*)(ylb + r0row * 512 + (kb ^ x0));
            bf16x8 a1h = *(const bf16x8*)(yhb + r1row * 512 + (kb ^ x1));
            bf16x8 a1l = *(const bf16x8*)(ylb + r1row * 512 + (kb ^ x1));
            acc0 = __builtin_amdgcn_mfma_f32_16x16x32_bf16(a0h, wbh[c], acc0, 0, 0, 0);
            acc0 = __builtin_amdgcn_mfma_f32_16x16x32_bf16(a0l, wbh[c], acc0, 0, 0, 0);
            acc0 = __builtin_amdgcn_mfma_f32_16x16x32_bf16(a0h, wbl[c], acc0, 0, 0, 0);
            acc1 = __builtin_amdgcn_mfma_f32_16x16x32_bf16(a1h, wbh[c], acc1, 0, 0, 0);
            acc1 = __builtin_amdgcn_mfma_f32_16x16x32_bf16(a1l, wbh[c], acc1, 0, 0, 0);
            acc1 = __builtin_amdgcn_mfma_f32_16x16x32_bf16(a1h, wbl[c], acc1, 0, 0, 0);
        }
        #pragma unroll
        for (int s = 0; s < 2; ++s) {
            #pragma unroll
            for (int r = 0; r < 4; ++r) {
                int row = s * 16 + 4 * l4 + r;
                int off = row * 128 + (((w * 16 + ln) * 2) ^ ((row & 7) << 4));
                float v = s ? acc1[r] : acc0[r];
                __bf16 h = (__bf16)v;
                *(__bf16*)(rhb + off) = h;
                *(__bf16*)(rlb + off) = (__bf16)(v - (float)h);
            }
        }
        __syncthreads();

        // ======== phase 2': g^T = W R^T  (4 dout-tiles x 2 row-tiles) ========
        f32x4 gt[4][2];
        #pragma unroll
        for (int dt = 0; dt < 4; ++dt)
            #pragma unroll
            for (int rt = 0; rt < 2; ++rt) gt[dt][rt] = (f32x4){0.f, 0.f, 0.f, 0.f};
        #pragma unroll
        for (int kc = 0; kc < 2; ++kc) {
            const int kb = kc * 64 + l4 * 16;
            bf16x8 bh[2], bl[2];
            #pragma unroll
            for (int rt = 0; rt < 2; ++rt) {
                const int rr = (16 * rt + ln) * 128;
                bh[rt] = *(const bf16x8*)(rhb + rr + (kb ^ rx));
                bl[rt] = *(const bf16x8*)(rlb + rr + (kb ^ rx));
            }
            #pragma unroll
            for (int dt = 0; dt < 4; ++dt) {
                const int jj = ((4 * w + dt) * 16 + ln) * 128;
                bf16x8 ah = *(const bf16x8*)(whb + jj + (kb ^ rx));
                #pragma unroll
                for (int rt = 0; rt < 2; ++rt) {
                    gt[dt][rt] = __builtin_amdgcn_mfma_f32_16x16x32_bf16(ah, bh[rt], gt[dt][rt], 0, 0, 0);
                    gt[dt][rt] = __builtin_amdgcn_mfma_f32_16x16x32_bf16(w2lo[dt][kc], bh[rt], gt[dt][rt], 0, 0, 0);
                    gt[dt][rt] = __builtin_amdgcn_mfma_f32_16x16x32_bf16(ah, bl[rt], gt[dt][rt], 0, 0, 0);
                }
            }
        }

        // ======== update: prox (med3 form, exact) + momentum; b64 y-writes ====
        const float t2v = 0.5f + 0.5f * sqrtf(1.f + 4.f * tt_ * tt_);
        const float mom = (tt_ - 1.f) / t2v;
        tt_ = t2v;
        #pragma unroll
        for (int dt = 0; dt < 4; ++dt)
          #pragma unroll
          for (int rt = 0; rt < 2; ++rt) {
              const int row  = 16 * rt + ln;
              const int colb = ((4 * w + dt) * 16 + 4 * l4) * 2;
              unsigned short hb[4], lb[4];
              #pragma unroll
              for (int r = 0; r < 4; ++r) {
                  float u  = ym[dt][rt][r] - c2 * gt[dt][rt][r];
                  float x2 = u - fminf(fmaxf(u, -thr), thr);    // == prox (exact)
                  float yn = x2 + mom * (x2 - xm[dt][rt][r]);
                  xm[dt][rt][r] = x2; ym[dt][rt][r] = yn;
                  __bf16 h = (__bf16)yn;
                  hb[r] = __builtin_bit_cast(unsigned short, h);
                  lb[r] = __builtin_bit_cast(unsigned short, (__bf16)(yn - (float)h));
              }
              const int off = row * 512 + (colb ^ ((row & 7) << 4));
              uint2 H, L;
              H.x = hb[0] | ((unsigned)hb[1] << 16); H.y = hb[2] | ((unsigned)hb[3] << 16);
              L.x = lb[0] | ((unsigned)lb[1] << 16); L.y = lb[2] | ((unsigned)lb[3] << 16);
              *(uint2*)(yhb + off) = H;
              *(uint2*)(ylb + off) = L;
          }
        __syncthreads();
    }

    // ---- store X (float4) ----
    #pragma unroll
    for (int dt = 0; dt < 4; ++dt)
      #pragma unroll
      for (int rt = 0; rt < 2; ++rt) {
          f32x4 o = { xm[dt][rt][0], xm[dt][rt][1], xm[dt][rt][2], xm[dt][rt][3] };
          *(f32x4*)&out[(size_t)(rb + 16 * rt + ln) * 256 + (4 * w + dt) * 16 + 4 * l4] = o;
      }
}

extern "C" void kernel_launch(void* const* d_in, const int* in_sizes, int n_in,
                              void* d_out, int out_size, void* d_ws, size_t ws_size,
                              hipStream_t stream) {
    (void)in_sizes; (void)n_in; (void)d_ws; (void)ws_size; (void)out_size;
    const float* inp = (const float*)d_in[0];   // [16384, 64]
    const float* Wg  = (const float*)d_in[1];   // [256, 64]
    const float* X0  = (const float*)d_in[2];   // [16384, 256]
    float* outp      = (float*)d_out;           // [16384, 256]
    fista11<<<16384 / ROWS, NTH, 0, stream>>>(inp, Wg, X0, outp);
}